// Round 12
// baseline (141.360 us; speedup 1.0000x reference)
//
#include <hip/hip_runtime.h>
#include <hip/hip_bf16.h>

// context_mapping on MI355X — round 11 kernel, second submission (round-11
// bench died on GPUAcquisitionTimeout — never executed, no signal).
// global_load_lds staging + counted vmcnt. Round-10 post-mortem: compiler
// SANK the register prefetch (VGPR stayed 80, not ~165) -> per-tile chain
// still exposes ~900cy HBM latency; 45us flat across 3 structures. Fix:
// async DMA staging (global_load_lds) which the compiler cannot sink,
// triple-buffered per-wave LDS, counted s_waitcnt vmcnt(N) so 2 stages stay
// in flight. No __syncthreads (per-wave buffers). Compute chain identical r9.

typedef __attribute__((ext_vector_type(8))) short bf16x8;
typedef __attribute__((ext_vector_type(4))) short s16x4;
typedef __attribute__((ext_vector_type(4))) float f32x4;

union B8 { bf16x8 v; short2 p[4]; int d[4]; };
union B4 { s16x4 v; short2 p[2]; int d[2]; };

__device__ __forceinline__ float lrelu(float x) { return fmaxf(x, 0.01f * x); }

__device__ __forceinline__ short2 cvt2(float a, float b) {
    __hip_bfloat162 h = __float22bfloat162_rn(make_float2(a, b));
    short2 s; __builtin_memcpy(&s, &h, 4); return s;
}

// async global->LDS, 16B per active lane, dest = uniform base + lane*16
__device__ __forceinline__ void gl16(const float* g, float* l) {
    __builtin_amdgcn_global_load_lds(
        (const __attribute__((address_space(1))) void*)g,
        (__attribute__((address_space(3))) void*)l, 16, 0, 0);
}

__global__ __launch_bounds__(256) void ctx_mfma(
    const float* __restrict__ lr,  const float* __restrict__ hr,
    const float* __restrict__ w0g, const float* __restrict__ w1g,
    const float* __restrict__ w2g, const float* __restrict__ w3g,
    const float* __restrict__ s0g, const float* __restrict__ s1g,
    const float* __restrict__ s2g, const float* __restrict__ wfg,
    float* __restrict__ out)
{
    constexpr int W = 1024, HW = 1024 * 1024, LHW = 256 * 256;

    // Per-wave triple-buffered staging: hr tile [16ch][16px], lr tile [16ch][4quad]
    __shared__ __align__(16) float shr[4][3][16][16];   // 12 KB
    __shared__ __align__(16) float slr[4][3][16][4];    //  3 KB

    const int tid  = threadIdx.x;
    const int lane = tid & 63;
    const int widx = tid >> 6;
    const int g    = lane >> 4;       // k-group 0..3
    const int px   = lane & 15;       // pixel-in-tile / weight-row index

    const int wave_id = blockIdx.x * 4 + widx;
    const int y  = wave_id >> 3;          // one row per 8 waves
    const int xw = (wave_id & 7) << 7;    // 128-px span

    // ---- weight A-fragments (A[m=px][k=8g+j]) ----
    B8 a1[2][2];
    #pragma unroll
    for (int m = 0; m < 2; ++m)
        #pragma unroll
        for (int q = 0; q < 2; ++q) {
            const float* wp = w0g + (m * 16 + px) * 64 + q * 32 + g * 8;
            #pragma unroll
            for (int j = 0; j < 4; ++j) a1[m][q].p[j] = cvt2(wp[2 * j], wp[2 * j + 1]);
        }
    B8 a2;
    {
        const float* wp = w1g + px * 32 + g * 8;
        #pragma unroll
        for (int j = 0; j < 4; ++j) a2.p[j] = cvt2(wp[2 * j], wp[2 * j + 1]);
    }
    B8 a3;   // W2 [8x16] zero-padded to [16x32]
    {
        const bool val = (px < 8) && (g < 2);
        const float* wp = w2g + (px & 7) * 16 + (g & 1) * 8;
        const short2 z2s = make_short2(0, 0);
        #pragma unroll
        for (int j = 0; j < 4; ++j) a3.p[j] = val ? cvt2(wp[2 * j], wp[2 * j + 1]) : z2s;
    }
    const float4 w3v = *(const float4*)(w3g + (g & 1) * 4);

    // ---- loop-invariant distance-net ----
    const int xi = px & 3, yi = y & 3;
    const float d0 = (float)xi + ((xi < 2) ? -2.f : -1.f);
    const float d1 = (float)yi + ((yi < 2) ? -2.f : -1.f);
    const float d2 = sqrtf(d0 * d0 + d1 * d1);
    const float q0 = lrelu(s0g[0] * d0 + s0g[1] * d1 + s0g[2] * d2);
    const float q1 = lrelu(s0g[3] * d0 + s0g[4] * d1 + s0g[5] * d2);
    const float q2 = lrelu(s0g[6] * d0 + s0g[7] * d1 + s0g[8] * d2);
    const float u0 = lrelu(s1g[0] * q0 + s1g[1] * q1 + s1g[2] * q2);
    const float u1 = lrelu(s1g[3] * q0 + s1g[4] * q1 + s1g[5] * q2);
    const float wt2 = lrelu(s2g[0] * u0 + s2g[1] * u1);
    const float awf0 = fabsf(wfg[0]), awf1 = fabsf(wfg[1]);

    // ---- shuffle source lanes (inter-layer redistribution, verified r9) ----
    const int s0l = px + 16 * ((2 * g) & 3);
    const int s1l = s0l + 16;
    const bool glo = (g < 2);
    const int cb = (g & 1) << 3;

    // ---- staging source addresses ----
    // hr: lane -> ch = lane>>2, quad = lane&3 (16B contiguous per lane)
    const float* hrs = hr + (lane >> 2) * HW + y * W + xw + (lane & 3) * 4;
    // lr: lanes 0-15 -> ch = lane (16B contiguous per lane)
    const float* lrs = lr + (lane & 15) * LHW + (y >> 2) * 256 + (xw >> 2);

    const int oidx = y * W + xw + px;
    const f32x4 zf = {0.f, 0.f, 0.f, 0.f};

#define STAGE(BUF, T)                                                         \
    {                                                                         \
        gl16(hrs + (T) * 16, &shr[widx][BUF][0][0]);                          \
        if (lane < 16) gl16(lrs + (T) * 4, &slr[widx][BUF][0][0]);            \
    }

#define COMP(BUF, T)                                                          \
    {                                                                         \
        float lrv[8], hrv[8];                                                 \
        _Pragma("unroll")                                                     \
        for (int j = 0; j < 8; ++j) {                                         \
            hrv[j] = shr[widx][BUF][cb + j][px];                              \
            lrv[j] = slr[widx][BUF][cb + j][px >> 2];                         \
        }                                                                     \
        B8 b0, b1;                                                            \
        _Pragma("unroll")                                                     \
        for (int j = 0; j < 4; ++j) {                                         \
            float ua = glo ? lrv[2 * j]     : hrv[2 * j];                     \
            float ub = glo ? lrv[2 * j + 1] : hrv[2 * j + 1];                 \
            b0.p[j] = cvt2(ua, ub);                                           \
            float da = lrv[2 * j]     - hrv[2 * j];                           \
            float db = lrv[2 * j + 1] - hrv[2 * j + 1];                       \
            float pa = glo ? lrv[2 * j]     * hrv[2 * j]     : da * da;       \
            float pb = glo ? lrv[2 * j + 1] * hrv[2 * j + 1] : db * db;       \
            b1.p[j] = cvt2(pa, pb);                                           \
        }                                                                     \
        f32x4 acc1a = __builtin_amdgcn_mfma_f32_16x16x32_bf16(a1[0][0].v, b0.v, zf, 0, 0, 0); \
        acc1a = __builtin_amdgcn_mfma_f32_16x16x32_bf16(a1[0][1].v, b1.v, acc1a, 0, 0, 0);    \
        f32x4 acc1b = __builtin_amdgcn_mfma_f32_16x16x32_bf16(a1[1][0].v, b0.v, zf, 0, 0, 0); \
        acc1b = __builtin_amdgcn_mfma_f32_16x16x32_bf16(a1[1][1].v, b1.v, acc1b, 0, 0, 0);    \
        B4 za, zq;                                                            \
        za.p[0] = cvt2(lrelu(acc1a.x), lrelu(acc1a.y));                       \
        za.p[1] = cvt2(lrelu(acc1a.z), lrelu(acc1a.w));                       \
        zq.p[0] = cvt2(lrelu(acc1b.x), lrelu(acc1b.y));                       \
        zq.p[1] = cvt2(lrelu(acc1b.z), lrelu(acc1b.w));                       \
        int A0 = __shfl(za.d[0], s0l, 64);                                    \
        int A1 = __shfl(za.d[1], s0l, 64);                                    \
        int A2 = __shfl(za.d[0], s1l, 64);                                    \
        int A3 = __shfl(za.d[1], s1l, 64);                                    \
        int Q0 = __shfl(zq.d[0], s0l, 64);                                    \
        int Q1 = __shfl(zq.d[1], s0l, 64);                                    \
        int Q2 = __shfl(zq.d[0], s1l, 64);                                    \
        int Q3 = __shfl(zq.d[1], s1l, 64);                                    \
        B8 b2;                                                                \
        b2.d[0] = glo ? A0 : Q0;                                              \
        b2.d[1] = glo ? A1 : Q1;                                              \
        b2.d[2] = glo ? A2 : Q2;                                              \
        b2.d[3] = glo ? A3 : Q3;                                              \
        f32x4 acc2 = __builtin_amdgcn_mfma_f32_16x16x32_bf16(a2.v, b2.v, zf, 0, 0, 0); \
        B4 z2q;                                                               \
        z2q.p[0] = cvt2(lrelu(acc2.x), lrelu(acc2.y));                        \
        z2q.p[1] = cvt2(lrelu(acc2.z), lrelu(acc2.w));                        \
        B8 b3;                                                                \
        b3.d[0] = __shfl(z2q.d[0], s0l, 64);                                  \
        b3.d[1] = __shfl(z2q.d[1], s0l, 64);                                  \
        b3.d[2] = __shfl(z2q.d[0], s1l, 64);                                  \
        b3.d[3] = __shfl(z2q.d[1], s1l, 64);                                  \
        f32x4 acc3 = __builtin_amdgcn_mfma_f32_16x16x32_bf16(a3.v, b3.v, zf, 0, 0, 0); \
        float part = w3v.x * lrelu(acc3.x) + w3v.y * lrelu(acc3.y)            \
                   + w3v.z * lrelu(acc3.z) + w3v.w * lrelu(acc3.w);           \
        float sum = part + __shfl_xor(part, 16, 64);                          \
        float wt1 = lrelu(sum);                                               \
        float res = lrelu(awf0 * wt1 + awf1 * wt2);                           \
        if (g == 0) out[oidx + (T) * 16] = res;                               \
    }

// Counted waits derived from the exact per-wave vmcnt op stream
// (2 stage ops/tile + 1 store/tile): allow {t+1,t+2} stages (+ interleaved
// stores) to remain outstanding; stricter = safe, looser = corruption.
#define WAITV(N) asm volatile("s_waitcnt vmcnt(" #N ")" ::: "memory")

    // prologue: 2 stages in flight
    STAGE(0, 0)
    STAGE(1, 1)
    STAGE(2, 2) WAITV(4); COMP(0, 0)
    STAGE(0, 3) WAITV(5); COMP(1, 1)
    STAGE(1, 4) WAITV(6); COMP(2, 2)
    STAGE(2, 5) WAITV(6); COMP(0, 3)
    STAGE(0, 6) WAITV(6); COMP(1, 4)
    STAGE(1, 7) WAITV(6); COMP(2, 5)
    WAITV(4); COMP(0, 6)
    WAITV(2); COMP(1, 7)

#undef STAGE
#undef COMP
#undef WAITV
}

extern "C" void kernel_launch(void* const* d_in, const int* in_sizes, int n_in,
                              void* d_out, int out_size, void* d_ws, size_t ws_size,
                              hipStream_t stream) {
    const float* lr = (const float*)d_in[0];
    const float* hr = (const float*)d_in[1];
    const float* w0 = (const float*)d_in[2];
    const float* w1 = (const float*)d_in[3];
    const float* w2 = (const float*)d_in[4];
    const float* w3 = (const float*)d_in[5];
    const float* s0 = (const float*)d_in[6];
    const float* s1 = (const float*)d_in[7];
    const float* s2 = (const float*)d_in[8];
    const float* wf = (const float*)d_in[9];
    float* o = (float*)d_out;

    // 65536 16-px tiles / 8 per wave = 8192 waves = 2048 blocks x 256 threads
    ctx_mfma<<<2048, 256, 0, stream>>>(lr, hr, w0, w1, w2, w3, s0, s1, s2, wf, o);
}

// Round 13
// 135.947 us; speedup vs baseline: 1.0398x; 1.0398x over previous
//
#include <hip/hip_runtime.h>
#include <hip/hip_bf16.h>

// context_mapping on MI355X — round 13: 32x32x16 MFMA + permlane32_swap.
// Rounds 4-12: five schedules all ~45-51us, same signature (VALU 42%, MFMA 5%,
// HBM 15%) -> transport/load mechanisms exonerated; limiter is instruction
// count x chain latency per pixel. This kernel halves both: 32px/tile,
// 7 MFMA (vs 12)/32px, 6 permlane32_swap (vs 24 bpermute)/32px, zero selects
// in b-frag/redistribution. D-layout 32x32 (m74/m101): row=(reg&3)+8*(reg>>2)
// +4h -> the L2/L3 B-operand exchange is exactly a lane<->lane+32 half-swap:
// one v_permlane32_swap_b32 yields BOTH needed dwords (r0={x.lo,y.lo},
// r1={x.hi,y.hi}). A/B k-slot packing uses the same kappa(h,j)=8h+j on both
// operands -> any true HW k-permutation cancels (same argument as r4, passed).
// lr: 32 loop-invariant regs (loaded once). hr: async-DMA staged, counted vmcnt.

typedef __attribute__((ext_vector_type(8))) short bf16x8;
typedef __attribute__((ext_vector_type(16))) float f32x16;

union B8 { bf16x8 v; short2 p[4]; int d[4]; };

__device__ __forceinline__ float lrelu(float x) { return fmaxf(x, 0.01f * x); }

__device__ __forceinline__ short2 cvt2(float a, float b) {
    __hip_bfloat162 h = __float22bfloat162_rn(make_float2(a, b));
    short2 s; __builtin_memcpy(&s, &h, 4); return s;
}
// pack two lrelu'd fp32 into one dword of 2 bf16
__device__ __forceinline__ int pk(float a, float b) {
    short2 s = cvt2(lrelu(a), lrelu(b));
    int r; __builtin_memcpy(&r, &s, 4); return r;
}

// async global->LDS, 16B per lane, dest = uniform base + lane*16
__device__ __forceinline__ void gl16(const float* g, float* l) {
    __builtin_amdgcn_global_load_lds(
        (const __attribute__((address_space(1))) void*)g,
        (__attribute__((address_space(3))) void*)l, 16, 0, 0);
}

// x,y <- {x.lo|y.lo}, {x.hi|y.hi}  (halves = lanes 0-31 / 32-63)
#define SWAP32(x, y) asm("v_permlane32_swap_b32 %0, %1" : "+v"(x), "+v"(y))

#define MFMA32(A, B, C) __builtin_amdgcn_mfma_f32_32x32x16_bf16((A), (B), (C), 0, 0, 0)

__global__ __launch_bounds__(256) void ctx_mfma(
    const float* __restrict__ lr,  const float* __restrict__ hr,
    const float* __restrict__ w0g, const float* __restrict__ w1g,
    const float* __restrict__ w2g, const float* __restrict__ w3g,
    const float* __restrict__ s0g, const float* __restrict__ s1g,
    const float* __restrict__ s2g, const float* __restrict__ wfg,
    float* __restrict__ out)
{
    constexpr int W = 1024, HW = 1024 * 1024, LHW = 256 * 256;

    // per-wave double-buffered hr staging: [16ch][32px] fp32 = 2KB per buffer
    __shared__ __align__(16) float shr[4][2][512];   // 16 KB

    const int tid  = threadIdx.x;
    const int lane = tid & 63;
    const int widx = tid >> 6;
    const int h    = lane >> 5;        // k-half 0/1
    const int px   = lane & 31;        // pixel-in-tile / weight-row index
    const int cb   = h << 3;           // channel base 0/8

    const int wave_id = blockIdx.x * 4 + widx;
    const int y  = wave_id >> 3;           // one row per 8 waves
    const int xw = (wave_id & 7) << 7;     // 128-px span = 4 tiles of 32

    // ---- A-fragments, kappa(h,j)=8h+j slot packing on A AND B ----
    B8 a1[4];                      // W0 [32rows][64k], k-quadrant q per MFMA
    #pragma unroll
    for (int q = 0; q < 4; ++q)
        #pragma unroll
        for (int j = 0; j < 4; ++j) {
            const float* wp = w0g + px * 64 + q * 16 + cb + 2 * j;
            a1[q].p[j] = cvt2(wp[0], wp[1]);
        }
    B8 a2[2];                      // W1 [16x32] zero-padded to 32 rows
    {
        const bool v2 = (px < 16);
        const short2 z2s = make_short2(0, 0);
        #pragma unroll
        for (int q = 0; q < 2; ++q)
            #pragma unroll
            for (int j = 0; j < 4; ++j) {
                const float* wp = w1g + (px & 15) * 32 + q * 16 + cb + 2 * j;
                a2[q].p[j] = v2 ? cvt2(wp[0], wp[1]) : z2s;
            }
    }
    B8 a3;                         // W2 [8x16] zero-padded to 32 rows
    {
        const bool v3 = (px < 8);
        const short2 z2s = make_short2(0, 0);
        #pragma unroll
        for (int j = 0; j < 4; ++j) {
            const float* wp = w2g + (px & 7) * 16 + cb + 2 * j;
            a3.p[j] = v3 ? cvt2(wp[0], wp[1]) : z2s;
        }
    }
    const float4 w3v = *(const float4*)(w3g + h * 4);   // rows 4h..4h+3

    // ---- loop-invariant distance-net (px&3, y&3) ----
    const int xi = px & 3, yi = y & 3;
    const float d0 = (float)xi + ((xi < 2) ? -2.f : -1.f);
    const float d1 = (float)yi + ((yi < 2) ? -2.f : -1.f);
    const float d2 = sqrtf(d0 * d0 + d1 * d1);
    const float q0 = lrelu(s0g[0] * d0 + s0g[1] * d1 + s0g[2] * d2);
    const float q1 = lrelu(s0g[3] * d0 + s0g[4] * d1 + s0g[5] * d2);
    const float q2 = lrelu(s0g[6] * d0 + s0g[7] * d1 + s0g[8] * d2);
    const float u0 = lrelu(s1g[0] * q0 + s1g[1] * q1 + s1g[2] * q2);
    const float u1 = lrelu(s1g[3] * q0 + s1g[4] * q1 + s1g[5] * q2);
    const float wt2 = lrelu(s2g[0] * u0 + s2g[1] * u1);
    const float awf0 = fabsf(wfg[0]), awf1 = fabsf(wfg[1]);

    // ---- lr: 32 loop-invariant registers (8 ch x 4 tiles) ----
    float lrq[8][4];
    const float* lrb = lr + (y >> 2) * 256 + (xw >> 2) + (px >> 2);
    #pragma unroll
    for (int j = 0; j < 8; ++j)
        #pragma unroll
        for (int t = 0; t < 4; ++t)
            lrq[j][t] = lrb[(cb + j) * LHW + t * 8];

    // ---- hr staging source (2 x gl16 per tile: ch 0-7, ch 8-15) ----
    const float* hrs = hr + (lane >> 3) * HW + y * W + xw + (lane & 7) * 4;
    float* lds0 = &shr[widx][0][0];
    float* lds1 = &shr[widx][1][0];

    const int oidx = y * W + xw + px;
    const f32x16 zf = {0.f};

#define STAGE(LP, T)                                                          \
    {                                                                         \
        gl16(hrs + (T) * 32, (LP));                                           \
        gl16(hrs + 8 * HW + (T) * 32, (LP) + 256);                            \
    }

#define COMP(LP, T)                                                          \
    {                                                                         \
        float hrv[8], lh[8], dd[8];                                          \
        _Pragma("unroll")                                                    \
        for (int j = 0; j < 8; ++j) hrv[j] = (LP)[(cb + j) * 32 + px];       \
        _Pragma("unroll")                                                    \
        for (int j = 0; j < 8; ++j) {                                        \
            float lv = lrq[j][T];                                            \
            lh[j] = lv * hrv[j];                                             \
            float da = lv - hrv[j];                                          \
            dd[j] = da * da;                                                 \
        }                                                                    \
        B8 b0, b1, b2, b3;                                                   \
        _Pragma("unroll")                                                    \
        for (int i = 0; i < 4; ++i) {                                        \
            b0.p[i] = cvt2(lrq[2 * i][T], lrq[2 * i + 1][T]);                \
            b1.p[i] = cvt2(hrv[2 * i], hrv[2 * i + 1]);                      \
            b2.p[i] = cvt2(lh[2 * i], lh[2 * i + 1]);                        \
            b3.p[i] = cvt2(dd[2 * i], dd[2 * i + 1]);                        \
        }                                                                    \
        f32x16 d1a = MFMA32(a1[0].v, b0.v, zf);                              \
        d1a = MFMA32(a1[1].v, b1.v, d1a);                                    \
        d1a = MFMA32(a1[2].v, b2.v, d1a);                                    \
        d1a = MFMA32(a1[3].v, b3.v, d1a);                                    \
        /* pack pairs; rows per reg: (reg&3)+8*(reg>>2)+4h */                \
        int P0 = pk(d1a[0],  d1a[1]),  P1 = pk(d1a[2],  d1a[3]);             \
        int P2 = pk(d1a[4],  d1a[5]),  P3 = pk(d1a[6],  d1a[7]);             \
        int P4 = pk(d1a[8],  d1a[9]),  P5 = pk(d1a[10], d1a[11]);            \
        int P6 = pk(d1a[12], d1a[13]), P7 = pk(d1a[14], d1a[15]);            \
        SWAP32(P0, P2); SWAP32(P1, P3);   /* B2a dwords P0,P1,P2,P3 */       \
        SWAP32(P4, P6); SWAP32(P5, P7);   /* B2b dwords P4,P5,P6,P7 */       \
        B8 b2a, b2b;                                                         \
        b2a.d[0] = P0; b2a.d[1] = P1; b2a.d[2] = P2; b2a.d[3] = P3;          \
        b2b.d[0] = P4; b2b.d[1] = P5; b2b.d[2] = P6; b2b.d[3] = P7;          \
        f32x16 d2a = MFMA32(a2[0].v, b2a.v, zf);                             \
        d2a = MFMA32(a2[1].v, b2b.v, d2a);                                   \
        int Q0 = pk(d2a[0], d2a[1]), Q1 = pk(d2a[2], d2a[3]);                \
        int Q2 = pk(d2a[4], d2a[5]), Q3 = pk(d2a[6], d2a[7]);                \
        SWAP32(Q0, Q2); SWAP32(Q1, Q3);                                      \
        B8 b3f;                                                              \
        b3f.d[0] = Q0; b3f.d[1] = Q1; b3f.d[2] = Q2; b3f.d[3] = Q3;          \
        f32x16 d3a = MFMA32(a3.v, b3f.v, zf);                                \
        float part = w3v.x * lrelu(d3a[0]) + w3v.y * lrelu(d3a[1])           \
                   + w3v.z * lrelu(d3a[2]) + w3v.w * lrelu(d3a[3]);          \
        float sum = part + __shfl_xor(part, 32, 64);                         \
        float wt1 = lrelu(sum);                                              \
        float res = lrelu(awf0 * wt1 + awf1 * wt2);                          \
        if (lane < 32) out[oidx + (T) * 32] = res;                           \
    }

#define WAITV(N) asm volatile("s_waitcnt vmcnt(" #N ")" ::: "memory")

    // ledger (2 stage-ops/STAGE, 1 store/COMP):
    // [s0,s0][s1,s1] W2 C0(st) [s2,s2] W3 C1(st) [s3,s3] W3 C2(st) W1 C3
    STAGE(lds0, 0)
    STAGE(lds1, 1)
    WAITV(2); COMP(lds0, 0)
    STAGE(lds0, 2)
    WAITV(3); COMP(lds1, 1)
    STAGE(lds1, 3)
    WAITV(3); COMP(lds0, 2)
    WAITV(1); COMP(lds1, 3)

#undef STAGE
#undef COMP
#undef WAITV
}

extern "C" void kernel_launch(void* const* d_in, const int* in_sizes, int n_in,
                              void* d_out, int out_size, void* d_ws, size_t ws_size,
                              hipStream_t stream) {
    const float* lr = (const float*)d_in[0];
    const float* hr = (const float*)d_in[1];
    const float* w0 = (const float*)d_in[2];
    const float* w1 = (const float*)d_in[3];
    const float* w2 = (const float*)d_in[4];
    const float* w3 = (const float*)d_in[5];
    const float* s0 = (const float*)d_in[6];
    const float* s1 = (const float*)d_in[7];
    const float* s2 = (const float*)d_in[8];
    const float* wf = (const float*)d_in[9];
    float* o = (float*)d_out;

    // 1M px / (4 waves x 4 tiles x 32 px) = 2048 blocks x 256 threads
    ctx_mfma<<<2048, 256, 0, stream>>>(lr, hr, w0, w1, w2, w3, s0, s1, s2, wf, o);
}